// Round 3
// baseline (900.128 us; speedup 1.0000x reference)
//
#include <hip/hip_runtime.h>

typedef __attribute__((ext_vector_type(8))) short short8;
typedef __attribute__((ext_vector_type(4))) float floatx4;
typedef __attribute__((ext_vector_type(2))) unsigned int uintx2;
typedef __attribute__((ext_vector_type(4))) unsigned int uintx4;

#define MFMA(a, b, c) __builtin_amdgcn_mfma_f32_16x16x32_bf16((a), (b), (c), 0, 0, 0)

__device__ __forceinline__ unsigned short f2bf(float f) {
  unsigned int u = __builtin_bit_cast(unsigned int, f);
  u += ((u >> 16) & 1u) + 0x7fffu;
  return (unsigned short)(u >> 16);
}

__device__ __forceinline__ float softplus_f(float v) {
  float a = __builtin_fabsf(v);
  float e = __expf(-a);
  float l = __logf(1.0f + e);
  return __builtin_fmaxf(v, 0.0f) + l;
}

__device__ __forceinline__ unsigned int pack_sp(float lo, float hi) {
  return (unsigned int)f2bf(softplus_f(lo)) | ((unsigned int)f2bf(softplus_f(hi)) << 16);
}

// 8B-granularity swizzle (at wave64-b64 bank floor): two b64 reads per 8-elem frag.
__device__ __forceinline__ short8 lds8(const unsigned short* s, int m, int k, int SE) {
  const int sw = (m & 15) << 2;
  const int e = m * SE + k;
  uintx2 lo = *(const uintx2*)(s + (e ^ sw));
  uintx2 hi = *(const uintx2*)(s + ((e + 4) ^ sw));
  uintx4 w;
  w.x = lo.x; w.y = lo.y; w.z = hi.x; w.w = hi.y;
  return __builtin_bit_cast(short8, w);
}

__device__ __forceinline__ void lds_st4(unsigned short* s, int m, int n, int SE, unsigned int w0,
                                        unsigned int w1) {
  const int e = (m * SE + n) ^ ((m & 15) << 2);
  uintx2 pk; pk.x = w0; pk.y = w1;
  *(uintx2*)(s + e) = pk;
}

// out[n*K + k] = bf16(in[k*N + n]); in is K x N row-major fp32
__global__ void transpose_cvt(const float* __restrict__ in, unsigned short* __restrict__ out,
                              int K, int N) {
  __shared__ float tile[32][33];
  const int bn = blockIdx.x * 32, bk = blockIdx.y * 32;
  const int tx = threadIdx.x, ty = threadIdx.y;  // 32 x 8
#pragma unroll
  for (int i = 0; i < 32; i += 8)
    tile[ty + i][tx] = in[(size_t)(bk + ty + i) * N + bn + tx];
  __syncthreads();
#pragma unroll
  for (int i = 0; i < 32; i += 8)
    out[(size_t)(bn + ty + i) * K + bk + tx] = f2bf(tile[tx][ty + i]);
}

// Fused MLP, transposed MFMA formulation: D[n][m] = sum_k Wt[n][k] * act[m][k].
// All 4 n-chunks of a layer kept live in registers (acc[4][2][4]) so the K-loop
// has 32 independent MFMAs per step (latency-proof) and B-frags are read once.
__global__ __launch_bounds__(512, 2) void mlp3(const float* __restrict__ x,
                                               const unsigned short* __restrict__ w1t,
                                               const unsigned short* __restrict__ w2t,
                                               const unsigned short* __restrict__ w3t,
                                               float* __restrict__ out) {
  __shared__ unsigned short h1s[64 * 1024];  // 128 KB: h1[m][n1] in G1/G2, h2[m][n2] in G3
  __shared__ unsigned short xs[64 * 256];    // 32 KB: x[m][k] bf16

  const int tid = threadIdx.x;
  const int lane = tid & 63;
  const int wv = tid >> 6;   // wave 0..7
  const int l15 = lane & 15;
  const int g = lane >> 4;   // 0..3
  const size_t m0 = (size_t)blockIdx.x * 64;

  const floatx4 z4 = {0.f, 0.f, 0.f, 0.f};

  // ---- stage x tile: 64x256 fp32 -> bf16 LDS ----
  {
    const float* xp = x + m0 * 256;
#pragma unroll
    for (int r = 0; r < 8; ++r) {
      int idx4 = r * 512 + tid;
      int m = idx4 >> 6;
      int k = (idx4 & 63) << 2;
      floatx4 v = *(const floatx4*)(xp + m * 256 + k);
      lds_st4(xs, m, k, 256,
              (unsigned int)f2bf(v.x) | ((unsigned int)f2bf(v.y) << 16),
              (unsigned int)f2bf(v.z) | ((unsigned int)f2bf(v.w) << 16));
    }
  }
  __syncthreads();

  // ---- G1: h1 = softplus(x @ W1); all 4 n1-chunks live; 8 k-steps of 32 ----
  {
    floatx4 acc1[4][2][4];
#pragma unroll
    for (int c = 0; c < 4; ++c)
#pragma unroll
      for (int t = 0; t < 2; ++t)
#pragma unroll
        for (int mt = 0; mt < 4; ++mt) acc1[c][t][mt] = z4;

    short8 a[4][2];
#pragma unroll
    for (int c = 0; c < 4; ++c)
#pragma unroll
      for (int t = 0; t < 2; ++t)
        a[c][t] = *(const short8*)(w1t + (size_t)(c * 256 + wv * 32 + t * 16 + l15) * 256 + g * 8);

#pragma unroll 2
    for (int ks = 0; ks < 8; ++ks) {
      const int kn = (ks < 7 ? ks + 1 : 7) * 32 + g * 8;
      short8 an[4][2];
#pragma unroll
      for (int c = 0; c < 4; ++c)
#pragma unroll
        for (int t = 0; t < 2; ++t)
          an[c][t] = *(const short8*)(w1t + (size_t)(c * 256 + wv * 32 + t * 16 + l15) * 256 + kn);
      const int k = ks * 32 + g * 8;
      short8 b0 = lds8(xs, 0 * 16 + l15, k, 256);
      short8 b1 = lds8(xs, 1 * 16 + l15, k, 256);
      short8 b2 = lds8(xs, 2 * 16 + l15, k, 256);
      short8 b3 = lds8(xs, 3 * 16 + l15, k, 256);
      __builtin_amdgcn_s_setprio(1);
#pragma unroll
      for (int c = 0; c < 4; ++c)
#pragma unroll
        for (int t = 0; t < 2; ++t) {
          acc1[c][t][0] = MFMA(a[c][t], b0, acc1[c][t][0]);
          acc1[c][t][1] = MFMA(a[c][t], b1, acc1[c][t][1]);
          acc1[c][t][2] = MFMA(a[c][t], b2, acc1[c][t][2]);
          acc1[c][t][3] = MFMA(a[c][t], b3, acc1[c][t][3]);
        }
      __builtin_amdgcn_s_setprio(0);
#pragma unroll
      for (int c = 0; c < 4; ++c)
#pragma unroll
        for (int t = 0; t < 2; ++t) a[c][t] = an[c][t];
    }

    // epilogue: softplus -> h1s[m][n1]
#pragma unroll
    for (int c = 0; c < 4; ++c)
#pragma unroll
      for (int t = 0; t < 2; ++t)
#pragma unroll
        for (int mt = 0; mt < 4; ++mt) {
          const int n1 = c * 256 + wv * 32 + t * 16 + g * 4;
          const int m = mt * 16 + l15;
          lds_st4(h1s, m, n1, 1024, pack_sp(acc1[c][t][mt].x, acc1[c][t][mt].y),
                  pack_sp(acc1[c][t][mt].z, acc1[c][t][mt].w));
        }
  }
  __syncthreads();

  // ---- G2: h2 = softplus(h1 @ W2); all 4 n2-chunks live; 32 k-steps of 32 ----
  {
    floatx4 acc2[4][2][4];
#pragma unroll
    for (int c = 0; c < 4; ++c)
#pragma unroll
      for (int t = 0; t < 2; ++t)
#pragma unroll
        for (int mt = 0; mt < 4; ++mt) acc2[c][t][mt] = z4;

    short8 a[4][2];
#pragma unroll
    for (int c = 0; c < 4; ++c)
#pragma unroll
      for (int t = 0; t < 2; ++t)
        a[c][t] = *(const short8*)(w2t + (size_t)(c * 256 + wv * 32 + t * 16 + l15) * 1024 + g * 8);

#pragma unroll 2
    for (int ks = 0; ks < 32; ++ks) {
      const int kn = (ks < 31 ? ks + 1 : 31) * 32 + g * 8;
      short8 an[4][2];
#pragma unroll
      for (int c = 0; c < 4; ++c)
#pragma unroll
        for (int t = 0; t < 2; ++t)
          an[c][t] =
              *(const short8*)(w2t + (size_t)(c * 256 + wv * 32 + t * 16 + l15) * 1024 + kn);
      const int k = ks * 32 + g * 8;
      short8 b0 = lds8(h1s, 0 * 16 + l15, k, 1024);
      short8 b1 = lds8(h1s, 1 * 16 + l15, k, 1024);
      short8 b2 = lds8(h1s, 2 * 16 + l15, k, 1024);
      short8 b3 = lds8(h1s, 3 * 16 + l15, k, 1024);
      __builtin_amdgcn_s_setprio(1);
#pragma unroll
      for (int c = 0; c < 4; ++c)
#pragma unroll
        for (int t = 0; t < 2; ++t) {
          acc2[c][t][0] = MFMA(a[c][t], b0, acc2[c][t][0]);
          acc2[c][t][1] = MFMA(a[c][t], b1, acc2[c][t][1]);
          acc2[c][t][2] = MFMA(a[c][t], b2, acc2[c][t][2]);
          acc2[c][t][3] = MFMA(a[c][t], b3, acc2[c][t][3]);
        }
      __builtin_amdgcn_s_setprio(0);
#pragma unroll
      for (int c = 0; c < 4; ++c)
#pragma unroll
        for (int t = 0; t < 2; ++t) a[c][t] = an[c][t];
    }

    __syncthreads();  // all waves done reading h1 from h1s before overwrite with h2

#pragma unroll
    for (int c = 0; c < 4; ++c)
#pragma unroll
      for (int t = 0; t < 2; ++t)
#pragma unroll
        for (int mt = 0; mt < 4; ++mt) {
          const int n2 = c * 256 + wv * 32 + t * 16 + g * 4;
          const int m = mt * 16 + l15;
          lds_st4(h1s, m, n2, 1024, pack_sp(acc2[c][t][mt].x, acc2[c][t][mt].y),
                  pack_sp(acc2[c][t][mt].z, acc2[c][t][mt].w));
        }
  }
  __syncthreads();

  // ---- G3: out = h2 @ W3; 16 k-steps of 64 ----
  {
    floatx4 acc3[2][4];
#pragma unroll
    for (int t = 0; t < 2; ++t)
#pragma unroll
      for (int mt = 0; mt < 4; ++mt) acc3[t][mt] = z4;

    short8 a[2][2];  // [k-half u][t]
#pragma unroll
    for (int u = 0; u < 2; ++u)
#pragma unroll
      for (int t = 0; t < 2; ++t)
        a[u][t] =
            *(const short8*)(w3t + (size_t)(wv * 32 + t * 16 + l15) * 1024 + u * 32 + g * 8);

#pragma unroll 2
    for (int ks = 0; ks < 16; ++ks) {
      const int knb = (ks < 15 ? ks + 1 : 15) * 64 + g * 8;
      short8 an[2][2];
#pragma unroll
      for (int u = 0; u < 2; ++u)
#pragma unroll
        for (int t = 0; t < 2; ++t)
          an[u][t] =
              *(const short8*)(w3t + (size_t)(wv * 32 + t * 16 + l15) * 1024 + knb + u * 32);
#pragma unroll
      for (int u = 0; u < 2; ++u) {
        const int k = ks * 64 + u * 32 + g * 8;
        short8 b0 = lds8(h1s, 0 * 16 + l15, k, 1024);
        short8 b1 = lds8(h1s, 1 * 16 + l15, k, 1024);
        short8 b2 = lds8(h1s, 2 * 16 + l15, k, 1024);
        short8 b3 = lds8(h1s, 3 * 16 + l15, k, 1024);
        __builtin_amdgcn_s_setprio(1);
#pragma unroll
        for (int t = 0; t < 2; ++t) {
          acc3[t][0] = MFMA(a[u][t], b0, acc3[t][0]);
          acc3[t][1] = MFMA(a[u][t], b1, acc3[t][1]);
          acc3[t][2] = MFMA(a[u][t], b2, acc3[t][2]);
          acc3[t][3] = MFMA(a[u][t], b3, acc3[t][3]);
        }
        __builtin_amdgcn_s_setprio(0);
      }
#pragma unroll
      for (int u = 0; u < 2; ++u)
#pragma unroll
        for (int t = 0; t < 2; ++t) a[u][t] = an[u][t];
    }

    // ---- store out[m][n3] fp32 ----
#pragma unroll
    for (int t = 0; t < 2; ++t)
#pragma unroll
      for (int mt = 0; mt < 4; ++mt) {
        const int n3 = wv * 32 + t * 16 + g * 4;
        const int m = mt * 16 + l15;
        *(floatx4*)(out + (m0 + m) * 256 + n3) = acc3[t][mt];
      }
  }
}

extern "C" void kernel_launch(void* const* d_in, const int* in_sizes, int n_in,
                              void* d_out, int out_size, void* d_ws, size_t ws_size,
                              hipStream_t stream) {
  const float* x = (const float*)d_in[0];
  const float* w1 = (const float*)d_in[1];
  const float* w2 = (const float*)d_in[2];
  const float* w3 = (const float*)d_in[3];
  float* out = (float*)d_out;

  unsigned short* w1t = (unsigned short*)d_ws;            // [1024][256]  bf16, 512 KB
  unsigned short* w2t = w1t + 1024 * 256;                 // [1024][1024] bf16, 2 MB
  unsigned short* w3t = w2t + 1024 * 1024;                // [256][1024]  bf16, 512 KB

  dim3 tb(32, 8);
  transpose_cvt<<<dim3(1024 / 32, 256 / 32), tb, 0, stream>>>(w1, w1t, 256, 1024);
  transpose_cvt<<<dim3(1024 / 32, 1024 / 32), tb, 0, stream>>>(w2, w2t, 1024, 1024);
  transpose_cvt<<<dim3(256 / 32, 1024 / 32), tb, 0, stream>>>(w3, w3t, 1024, 256);

  mlp3<<<131072 / 64, 512, 0, stream>>>(x, w1t, w2t, w3t, out);
}